// Round 3
// baseline (2212.354 us; speedup 1.0000x reference)
//
#include <hip/hip_runtime.h>
#include <math.h>

#define V 64
#define TMAX 2048
#define ED 512
#define H 64
#define G3 192

// packed fp32 FMA: acc.{x,y} += a.{x,y} * b.{x,y}  (one VALU instr, gfx90a+)
__device__ __forceinline__ void pk_fma(float2& acc, float2 a, float2 b) {
    asm("v_pk_fma_f32 %0, %1, %2, %0" : "+v"(acc) : "v"(a), "v"(b));
}

// ---------------- K0: zero the persistent hidden state ----------------
__global__ void k_init(float* __restrict__ h) {
    int i = blockIdx.x * blockDim.x + threadIdx.x;
    if (i < V * H) h[i] = 0.f;
}

// ---------------- K1: xg[v, tl, g] = b_ih[g] + sum_k emb[v,t,k] * W_ih[g,k]
// 128t x 192g block tile, 8t x 12g register micro-tile per thread.
// XOR column swizzle on LDS (row stride 64 floats, no pad).
__global__ __launch_bounds__(256) void k_gemm(
    const float* __restrict__ emb, const int* __restrict__ lengths,
    const float* __restrict__ W_ih, const float* __restrict__ b_ih,
    float* __restrict__ xg, int c, int CT) {
    int v   = blockIdx.y;
    int tl0 = blockIdx.x * 128;
    int t0  = c * CT + tl0;
    int len = lengths[v];
    if (t0 >= len) return;  // nothing in this tile is ever read

    __shared__ __align__(16) float Es[128 * 64];  // 32 KB, swizzled
    __shared__ __align__(16) float Ws[G3 * 64];   // 48 KB, swizzled

    int th = threadIdx.x;
    int tb = th & 15;   // t-block: rows tb*8 .. tb*8+7
    int gb = th >> 4;   // g-block: gates gb*12 .. gb*12+11
    int eswz = tb & 7;  // read-side swizzle for this thread's 8 E rows

    float acc[8][12];
#pragma unroll
    for (int i = 0; i < 8; i++)
#pragma unroll
        for (int j = 0; j < 12; j++) acc[i][j] = 0.f;

    const float* ebase = emb + (size_t)(v * TMAX + t0) * ED;

    for (int kc = 0; kc < 8; kc++) {
        // stage E tile: 128x64 floats = 2048 float4, 8 per thread
#pragma unroll
        for (int r = 0; r < 8; r++) {
            int i = th + r * 256;
            int row = i >> 4, pos = i & 15;
            *(float4*)&Es[row * 64 + (pos ^ ((row >> 3) & 7)) * 4] =
                *(const float4*)&ebase[(size_t)row * ED + kc * 64 + pos * 4];
        }
        // stage W tile: 192x64 floats = 3072 float4, 12 per thread
#pragma unroll
        for (int r = 0; r < 12; r++) {
            int i = th + r * 256;
            int row = i >> 4, pos = i & 15;
            *(float4*)&Ws[row * 64 + (pos ^ (row & 7)) * 4] =
                *(const float4*)&W_ih[(size_t)row * ED + kc * 64 + pos * 4];
        }
        __syncthreads();
#pragma unroll 2
        for (int k4 = 0; k4 < 16; k4++) {
            float4 e[8];
#pragma unroll
            for (int i = 0; i < 8; i++)
                e[i] = *(float4*)&Es[(tb * 8 + i) * 64 + (k4 ^ eswz) * 4];
#pragma unroll
            for (int j = 0; j < 12; j++) {
                int g = gb * 12 + j;
                float4 w = *(float4*)&Ws[g * 64 + (k4 ^ (g & 7)) * 4];
#pragma unroll
                for (int i = 0; i < 8; i++)
                    acc[i][j] += e[i].x * w.x + e[i].y * w.y + e[i].z * w.z + e[i].w * w.w;
            }
        }
        __syncthreads();
    }

    float4 bv[3];
#pragma unroll
    for (int j4 = 0; j4 < 3; j4++)
        bv[j4] = *(const float4*)&b_ih[gb * 12 + j4 * 4];

#pragma unroll
    for (int i = 0; i < 8; i++) {
        size_t ob = ((size_t)(v * CT + tl0 + tb * 8 + i)) * G3 + gb * 12;
#pragma unroll
        for (int j4 = 0; j4 < 3; j4++) {
            float4 o;
            o.x = acc[i][j4 * 4 + 0] + bv[j4].x;
            o.y = acc[i][j4 * 4 + 1] + bv[j4].y;
            o.z = acc[i][j4 * 4 + 2] + bv[j4].z;
            o.w = acc[i][j4 * 4 + 3] + bv[j4].w;
            *(float4*)&xg[ob + j4 * 4] = o;
        }
    }
}

// ---------------- K1s: small-CT fallback (32x192 tile) ----------------
__global__ __launch_bounds__(256) void k_gemm_s(
    const float* __restrict__ emb, const int* __restrict__ lengths,
    const float* __restrict__ W_ih, const float* __restrict__ b_ih,
    float* __restrict__ xg, int c, int CT) {
    int v   = blockIdx.y;
    int tl0 = blockIdx.x * 32;
    int t0  = c * CT + tl0;
    int len = lengths[v];
    if (t0 >= len) return;

    __shared__ __align__(16) float Es[32][68];
    __shared__ __align__(16) float Ws[G3][68];

    int th = threadIdx.x;
    int tq = th & 31;
    int gq = th >> 5;

    float acc[24];
#pragma unroll
    for (int j = 0; j < 24; j++) acc[j] = 0.f;

    for (int kc = 0; kc < 8; kc++) {
#pragma unroll
        for (int r = 0; r < 2; r++) {
            int i = th + r * 256;
            int row = i >> 4, pos = i & 15;
            *(float4*)&Es[row][pos * 4] =
                *(const float4*)&emb[((size_t)(v * TMAX + t0 + row)) * ED + kc * 64 + pos * 4];
        }
#pragma unroll
        for (int r = 0; r < 12; r++) {
            int i = th + r * 256;
            int row = i >> 4, pos = i & 15;
            *(float4*)&Ws[row][pos * 4] =
                *(const float4*)&W_ih[(size_t)row * ED + kc * 64 + pos * 4];
        }
        __syncthreads();
#pragma unroll
        for (int k4 = 0; k4 < 16; k4++) {
            float4 e4 = *(float4*)&Es[tq][k4 * 4];
#pragma unroll
            for (int j = 0; j < 24; j++) {
                float4 w4 = *(float4*)&Ws[gq * 24 + j][k4 * 4];
                acc[j] += e4.x * w4.x + e4.y * w4.y + e4.z * w4.z + e4.w * w4.w;
            }
        }
        __syncthreads();
    }

    size_t ob = ((size_t)(v * CT + tl0 + tq)) * G3 + gq * 24;
#pragma unroll
    for (int j4 = 0; j4 < 6; j4++) {
        float4 o;
        o.x = acc[j4 * 4 + 0] + b_ih[gq * 24 + j4 * 4 + 0];
        o.y = acc[j4 * 4 + 1] + b_ih[gq * 24 + j4 * 4 + 1];
        o.z = acc[j4 * 4 + 2] + b_ih[gq * 24 + j4 * 4 + 2];
        o.w = acc[j4 * 4 + 3] + b_ih[gq * 24 + j4 * 4 + 3];
        *(float4*)&xg[ob + j4 * 4] = o;
    }
}

// ---------------- K2: sequential GRU recurrence.
// v4: single wave per variable, all 3 gates per lane (W_hh rows {i,64+i,128+i}
// in 192 VGPRs). v3 SPILLED (VGPR_Count=124 < 192 needed) because
// __launch_bounds__(64) without min-waves let the allocator target occupancy;
// (64, 1) raises the cap to 512 VGPRs -> no spill. Occupancy is irrelevant:
// 64 single-wave blocks on 256 CUs.
// xg prefetch depth 2 (xg is L3-resident, ~500cyc; step body ~300cyc).
__global__ __launch_bounds__(64, 1) void k_rec(
    const float* __restrict__ xg, const int* __restrict__ lengths,
    const float* __restrict__ W_hh, const float* __restrict__ b_hh,
    float* __restrict__ h, int c, int CT) {
    int v = blockIdx.x;
    int i = threadIdx.x;  // 0..63 = hidden index
    int len = lengths[v];
    int rem = len - c * CT;
    int tcnt = rem < 0 ? 0 : (rem > CT ? CT : rem);

    __shared__ __align__(16) float hs[H];

    // own weight rows as float2[32] each (192 VGPRs)
    float2 wr[32], wz[32], wn[32];
    {
        const float2* Wr = (const float2*)&W_hh[(size_t)i * H];
        const float2* Wz = (const float2*)&W_hh[(size_t)(64 + i) * H];
        const float2* Wn = (const float2*)&W_hh[(size_t)(128 + i) * H];
#pragma unroll
        for (int k = 0; k < 32; k++) { wr[k] = Wr[k]; wz[k] = Wz[k]; wn[k] = Wn[k]; }
    }
    float br = b_hh[i], bz = b_hh[64 + i], bn = b_hh[128 + i];

    float hown = h[v * H + i];
    hs[i] = hown;
    // single wave: lockstep guarantees hs[i] store precedes any lane's reads

    const float* xgv = xg + (size_t)v * CT * G3;
    // prefetch pipeline, depth 2
    float xr = 0.f, xz = 0.f, xn = 0.f;   // step t
    float yr = 0.f, yz = 0.f, yn = 0.f;   // step t+1
    if (tcnt > 0) { xr = xgv[i]; xz = xgv[64 + i]; xn = xgv[128 + i]; }
    if (tcnt > 1) {
        const float* p = xgv + (size_t)G3;
        yr = p[i]; yz = p[64 + i]; yn = p[128 + i];
    }

    for (int t = 0; t < tcnt; t++) {
        // issue load for step t+2 immediately (independent of the chain)
        float pr = 0.f, pz = 0.f, pn = 0.f;
        if (t + 2 < tcnt) {
            const float* p = xgv + (size_t)(t + 2) * G3;
            pr = p[i]; pz = p[64 + i]; pn = p[128 + i];
        }
        // broadcast-read h (uniform address -> LDS broadcast, conflict-free)
        float2 ar0 = {0.f,0.f}, ar1 = {0.f,0.f};
        float2 az0 = {0.f,0.f}, az1 = {0.f,0.f};
        float2 an0 = {0.f,0.f}, an1 = {0.f,0.f};
#pragma unroll
        for (int q = 0; q < 16; q++) {
            float4 h4 = *(const float4*)&hs[q * 4];
            float2 hlo = make_float2(h4.x, h4.y);
            float2 hhi = make_float2(h4.z, h4.w);
            pk_fma(ar0, wr[2 * q],     hlo);
            pk_fma(ar1, wr[2 * q + 1], hhi);
            pk_fma(az0, wz[2 * q],     hlo);
            pk_fma(az1, wz[2 * q + 1], hhi);
            pk_fma(an0, wn[2 * q],     hlo);
            pk_fma(an1, wn[2 * q + 1], hhi);
        }
        float hr = br + ((ar0.x + ar0.y) + (ar1.x + ar1.y));
        float hz = bz + ((az0.x + az0.y) + (az1.x + az1.y));
        float hn = bn + ((an0.x + an0.y) + (an1.x + an1.y));

        float r = __fdividef(1.f, 1.f + __expf(-(hr + xr)));
        float z = __fdividef(1.f, 1.f + __expf(-(hz + xz)));
        float pre = xn + r * hn;
        float e2 = __expf(2.f * pre);
        float n = 1.f - __fdividef(2.f, e2 + 1.f);
        hown = (1.f - z) * n + z * hown;

        // lockstep: every lane finished its hs reads (program order) before
        // any lane executes this store. No barrier needed in a single wave.
        hs[i] = hown;
        xr = yr; xz = yz; xn = yn;
        yr = pr; yz = pz; yn = pn;
    }
    if (tcnt > 0) h[v * H + i] = hown;
}

// ---------------- K2F: fully-fused fallback (tiny workspace). Slow but correct.
__global__ __launch_bounds__(192) void k_rec_fused(
    const float* __restrict__ emb, const int* __restrict__ lengths,
    const float* __restrict__ W_ih, const float* __restrict__ b_ih,
    const float* __restrict__ W_hh, const float* __restrict__ b_hh,
    float* __restrict__ h) {
    int v  = blockIdx.x;
    int th = threadIdx.x;
    int len = lengths[v];

    __shared__ __align__(16) float hs[H];
    __shared__ __align__(16) float es[ED];
    __shared__ float znbuf[128];
    __shared__ float xnbuf[64];

    float4 w4[16];
#pragma unroll
    for (int k4 = 0; k4 < 16; k4++)
        w4[k4] = *(const float4*)&W_hh[(size_t)th * H + k4 * 4];
    float bhh = b_hh[th];
    float bih = b_ih[th];
    if (th < H) hs[th] = 0.f;
    const float* ev = emb + (size_t)v * TMAX * ED;
    const float* wrow = W_ih + (size_t)th * ED;

    for (int t = 0; t < len; t++) {
        __syncthreads();
        for (int i = th; i < 128; i += 192)
            *(float4*)&es[i * 4] = *(const float4*)&ev[(size_t)t * ED + i * 4];
        __syncthreads();
        float xgt = bih;
        for (int k4 = 0; k4 < 128; k4++) {
            float4 wv = *(const float4*)&wrow[k4 * 4];
            float4 e4 = *(float4*)&es[k4 * 4];
            xgt += wv.x * e4.x + wv.y * e4.y + wv.z * e4.z + wv.w * e4.w;
        }
        float hg = bhh;
#pragma unroll
        for (int k4 = 0; k4 < 16; k4++) {
            float4 h4 = *(float4*)&hs[k4 * 4];
            hg += w4[k4].x * h4.x + w4[k4].y * h4.y + w4[k4].z * h4.z + w4[k4].w * h4.w;
        }
        if (th >= H && th < 128) znbuf[th - H] = hg + xgt;
        if (th >= 128) { znbuf[th - H] = hg; xnbuf[th - 128] = xgt; }
        __syncthreads();
        if (th < H) {
            float r = 1.f / (1.f + expf(-(hg + xgt)));
            float z = 1.f / (1.f + expf(-znbuf[th]));
            float n = tanhf(xnbuf[th] + r * znbuf[64 + th]);
            float hold = hs[th];
            hs[th] = (1.f - z) * n + z * hold;
        }
    }
    __syncthreads();
    if (th < H) h[v * H + th] = hs[th];
}

// ---------------- K3a: hid[o] = relu(b1[o] + W1[o,:] · concat)
__global__ __launch_bounds__(256) void k_mlp1(
    const float* __restrict__ h, const float* __restrict__ W1,
    const float* __restrict__ b1, float* __restrict__ hid) {
    int o = blockIdx.x, th = threadIdx.x;
    const float* w = W1 + (size_t)o * (V * H);
    float s = 0.f;
#pragma unroll
    for (int r = 0; r < 4; r++) {
        int i = (th + r * 256) * 4;
        float4 a = *(const float4*)&w[i];
        float4 b = *(const float4*)&h[i];
        s += a.x * b.x + a.y * b.y + a.z * b.z + a.w * b.w;
    }
    __shared__ float red[4];
    for (int off = 32; off; off >>= 1) s += __shfl_down(s, off);
    if ((th & 63) == 0) red[th >> 6] = s;
    __syncthreads();
    if (th == 0) {
        float tot = red[0] + red[1] + red[2] + red[3] + b1[o];
        hid[o] = tot > 0.f ? tot : 0.f;
    }
}

// ---------------- K3b: out = b2 + W2 · hid
__global__ void k_mlp2(const float* __restrict__ hid, const float* __restrict__ W2,
                       const float* __restrict__ b2, float* __restrict__ out) {
    int th = threadIdx.x;
    float s = hid[th] * W2[th];
    for (int off = 32; off; off >>= 1) s += __shfl_down(s, off);
    if (th == 0) out[0] = s + b2[0];
}

extern "C" void kernel_launch(void* const* d_in, const int* in_sizes, int n_in,
                              void* d_out, int out_size, void* d_ws, size_t ws_size,
                              hipStream_t stream) {
    const float* emb     = (const float*)d_in[0];
    const int*   lengths = (const int*)d_in[1];
    const float* W_ih    = (const float*)d_in[2];
    const float* W_hh    = (const float*)d_in[3];
    const float* b_ih    = (const float*)d_in[4];
    const float* b_hh    = (const float*)d_in[5];
    const float* W1      = (const float*)d_in[6];
    const float* b1      = (const float*)d_in[7];
    const float* W2      = (const float*)d_in[8];
    const float* b2      = (const float*)d_in[9];
    float* out = (float*)d_out;
    float* wsf = (float*)d_ws;

    const size_t tail = (size_t)V * H + V;  // h + hid (floats)
    int CT = 0;
    const int cts[7] = {2048, 1024, 512, 256, 128, 64, 32};
    for (int i = 0; i < 7; i++) {
        size_t need = ((size_t)V * cts[i] * G3 + tail) * sizeof(float);
        if (need <= ws_size) { CT = cts[i]; break; }
    }

    if (CT > 0) {
        float* xg  = wsf;
        float* hbf = wsf + (size_t)V * CT * G3;
        float* hid = hbf + (size_t)V * H;
        k_init<<<dim3((V * H + 255) / 256), dim3(256), 0, stream>>>(hbf);
        int nch = TMAX / CT;
        for (int c = 0; c < nch; c++) {
            if (CT >= 256)
                k_gemm<<<dim3(CT / 128, V), dim3(256), 0, stream>>>(emb, lengths, W_ih, b_ih, xg, c, CT);
            else
                k_gemm_s<<<dim3(CT / 32, V), dim3(256), 0, stream>>>(emb, lengths, W_ih, b_ih, xg, c, CT);
            k_rec<<<dim3(V), dim3(64), 0, stream>>>(xg, lengths, W_hh, b_hh, hbf, c, CT);
        }
        k_mlp1<<<dim3(V), dim3(256), 0, stream>>>(hbf, W1, b1, hid);
        k_mlp2<<<dim3(1), dim3(64), 0, stream>>>(hid, W2, b2, out);
    } else {
        float* hbf = wsf;
        float* hid = hbf + (size_t)V * H;
        k_rec_fused<<<dim3(V), dim3(G3), 0, stream>>>(emb, lengths, W_ih, b_ih, W_hh, b_hh, hbf);
        k_mlp1<<<dim3(V), dim3(256), 0, stream>>>(hbf, W1, b1, hid);
        k_mlp2<<<dim3(1), dim3(64), 0, stream>>>(hid, W2, b2, out);
    }
}

// Round 4
// 2019.549 us; speedup vs baseline: 1.0955x; 1.0955x over previous
//
#include <hip/hip_runtime.h>
#include <math.h>

#define V 64
#define TMAX 2048
#define ED 512
#define H 64
#define G3 192

// packed fp32 FMA: acc.{x,y} += a.{x,y} * b.{x,y}  (one VALU instr)
__device__ __forceinline__ void pk_fma(float2& acc, float2 a, float2 b) {
    asm("v_pk_fma_f32 %0, %1, %2, %0" : "+v"(acc) : "v"(a), "v"(b));
}

// ---------------- K0: zero the persistent hidden state ----------------
__global__ void k_init(float* __restrict__ h) {
    int i = blockIdx.x * blockDim.x + threadIdx.x;
    if (i < V * H) h[i] = 0.f;
}

// ---------------- K1: xg[v, tl, g] = b_ih[g] + sum_k emb[v,t,k] * W_ih[g,k]
// 128t x 192g block tile, 8t x 12g register micro-tile per thread.
// XOR column swizzle on LDS (row stride 64 floats, no pad).
// waves_per_eu(2,2): cap 256 VGPR (acc 96 + e 32 + addr ~30 fits, no spill);
// real occupancy is LDS-limited to 2 blocks/CU = 2 waves/EU anyway.
__global__ __launch_bounds__(256)
__attribute__((amdgpu_waves_per_eu(2, 2))) void k_gemm(
    const float* __restrict__ emb, const int* __restrict__ lengths,
    const float* __restrict__ W_ih, const float* __restrict__ b_ih,
    float* __restrict__ xg, int c, int CT) {
    int v   = blockIdx.y;
    int tl0 = blockIdx.x * 128;
    int t0  = c * CT + tl0;
    int len = lengths[v];
    if (t0 >= len) return;  // nothing in this tile is ever read

    __shared__ __align__(16) float Es[128 * 64];  // 32 KB, swizzled
    __shared__ __align__(16) float Ws[G3 * 64];   // 48 KB, swizzled

    int th = threadIdx.x;
    int tb = th & 15;   // t-block: rows tb*8 .. tb*8+7
    int gb = th >> 4;   // g-block: gates gb*12 .. gb*12+11
    int eswz = tb & 7;  // read-side swizzle for this thread's 8 E rows

    float acc[8][12];
#pragma unroll
    for (int i = 0; i < 8; i++)
#pragma unroll
        for (int j = 0; j < 12; j++) acc[i][j] = 0.f;

    const float* ebase = emb + (size_t)(v * TMAX + t0) * ED;

    for (int kc = 0; kc < 8; kc++) {
        // stage E tile: 128x64 floats = 2048 float4, 8 per thread
#pragma unroll
        for (int r = 0; r < 8; r++) {
            int i = th + r * 256;
            int row = i >> 4, pos = i & 15;
            *(float4*)&Es[row * 64 + (pos ^ ((row >> 3) & 7)) * 4] =
                *(const float4*)&ebase[(size_t)row * ED + kc * 64 + pos * 4];
        }
        // stage W tile: 192x64 floats = 3072 float4, 12 per thread
#pragma unroll
        for (int r = 0; r < 12; r++) {
            int i = th + r * 256;
            int row = i >> 4, pos = i & 15;
            *(float4*)&Ws[row * 64 + (pos ^ (row & 7)) * 4] =
                *(const float4*)&W_ih[(size_t)row * ED + kc * 64 + pos * 4];
        }
        __syncthreads();
#pragma unroll 2
        for (int k4 = 0; k4 < 16; k4++) {
            float4 e[8];
#pragma unroll
            for (int i = 0; i < 8; i++)
                e[i] = *(float4*)&Es[(tb * 8 + i) * 64 + (k4 ^ eswz) * 4];
#pragma unroll
            for (int j = 0; j < 12; j++) {
                int g = gb * 12 + j;
                float4 w = *(float4*)&Ws[g * 64 + (k4 ^ (g & 7)) * 4];
#pragma unroll
                for (int i = 0; i < 8; i++)
                    acc[i][j] += e[i].x * w.x + e[i].y * w.y + e[i].z * w.z + e[i].w * w.w;
            }
        }
        __syncthreads();
    }

    float4 bv[3];
#pragma unroll
    for (int j4 = 0; j4 < 3; j4++)
        bv[j4] = *(const float4*)&b_ih[gb * 12 + j4 * 4];

#pragma unroll
    for (int i = 0; i < 8; i++) {
        size_t ob = ((size_t)(v * CT + tl0 + tb * 8 + i)) * G3 + gb * 12;
#pragma unroll
        for (int j4 = 0; j4 < 3; j4++) {
            float4 o;
            o.x = acc[i][j4 * 4 + 0] + bv[j4].x;
            o.y = acc[i][j4 * 4 + 1] + bv[j4].y;
            o.z = acc[i][j4 * 4 + 2] + bv[j4].z;
            o.w = acc[i][j4 * 4 + 3] + bv[j4].w;
            *(float4*)&xg[ob + j4 * 4] = o;
        }
    }
}

// ---------------- K1s: small-CT fallback (32x192 tile) ----------------
__global__ __launch_bounds__(256) void k_gemm_s(
    const float* __restrict__ emb, const int* __restrict__ lengths,
    const float* __restrict__ W_ih, const float* __restrict__ b_ih,
    float* __restrict__ xg, int c, int CT) {
    int v   = blockIdx.y;
    int tl0 = blockIdx.x * 32;
    int t0  = c * CT + tl0;
    int len = lengths[v];
    if (t0 >= len) return;

    __shared__ __align__(16) float Es[32][68];
    __shared__ __align__(16) float Ws[G3][68];

    int th = threadIdx.x;
    int tq = th & 31;
    int gq = th >> 5;

    float acc[24];
#pragma unroll
    for (int j = 0; j < 24; j++) acc[j] = 0.f;

    for (int kc = 0; kc < 8; kc++) {
#pragma unroll
        for (int r = 0; r < 2; r++) {
            int i = th + r * 256;
            int row = i >> 4, pos = i & 15;
            *(float4*)&Es[row][pos * 4] =
                *(const float4*)&emb[((size_t)(v * TMAX + t0 + row)) * ED + kc * 64 + pos * 4];
        }
#pragma unroll
        for (int r = 0; r < 12; r++) {
            int i = th + r * 256;
            int row = i >> 4, pos = i & 15;
            *(float4*)&Ws[row][pos * 4] =
                *(const float4*)&W_ih[(size_t)row * ED + kc * 64 + pos * 4];
        }
        __syncthreads();
#pragma unroll
        for (int k4 = 0; k4 < 16; k4++) {
            float4 e4 = *(float4*)&Es[tq][k4 * 4];
#pragma unroll
            for (int j = 0; j < 24; j++) {
                float4 w4 = *(float4*)&Ws[gq * 24 + j][k4 * 4];
                acc[j] += e4.x * w4.x + e4.y * w4.y + e4.z * w4.z + e4.w * w4.w;
            }
        }
        __syncthreads();
    }

    size_t ob = ((size_t)(v * CT + tl0 + tq)) * G3 + gq * 24;
#pragma unroll
    for (int j4 = 0; j4 < 6; j4++) {
        float4 o;
        o.x = acc[j4 * 4 + 0] + b_ih[gq * 24 + j4 * 4 + 0];
        o.y = acc[j4 * 4 + 1] + b_ih[gq * 24 + j4 * 4 + 1];
        o.z = acc[j4 * 4 + 2] + b_ih[gq * 24 + j4 * 4 + 2];
        o.w = acc[j4 * 4 + 3] + b_ih[gq * 24 + j4 * 4 + 3];
        *(float4*)&xg[ob + j4 * 4] = o;
    }
}

// one GRU timestep: xr/xz/xn are this step's input-gate values; TT is the
// global step index (dead steps TT>=tcnt compute finite garbage, discarded
// by the cndmask on hown; hs rewrite of unchanged hown is harmless).
#define GRU_STEP(XR, XZ, XN, TT)                                            \
  {                                                                         \
    float2 ar0={0.f,0.f}, ar1={0.f,0.f}, az0={0.f,0.f}, az1={0.f,0.f},      \
           an0={0.f,0.f}, an1={0.f,0.f};                                    \
    _Pragma("unroll")                                                       \
    for (int q = 0; q < 16; q++) {                                          \
      float4 h4 = *(const float4*)&hs[q * 4];                               \
      float2 hlo = make_float2(h4.x, h4.y);                                 \
      float2 hhi = make_float2(h4.z, h4.w);                                 \
      pk_fma(ar0, wr[2*q], hlo);  pk_fma(ar1, wr[2*q+1], hhi);              \
      pk_fma(az0, wz[2*q], hlo);  pk_fma(az1, wz[2*q+1], hhi);              \
      pk_fma(an0, wn[2*q], hlo);  pk_fma(an1, wn[2*q+1], hhi);              \
    }                                                                       \
    float hr = br + ((ar0.x+ar0.y)+(ar1.x+ar1.y));                          \
    float hz = bz + ((az0.x+az0.y)+(az1.x+az1.y));                          \
    float hn = bn + ((an0.x+an0.y)+(an1.x+an1.y));                          \
    float r_ = __fdividef(1.f, 1.f + __expf(-(hr + (XR))));                 \
    float z_ = __fdividef(1.f, 1.f + __expf(-(hz + (XZ))));                 \
    float e2 = __expf(2.f * ((XN) + r_ * hn));                              \
    float n_ = 1.f - __fdividef(2.f, e2 + 1.f);                             \
    float hnew = (1.f - z_) * n_ + z_ * hown;                               \
    hown = ((TT) < tcnt) ? hnew : hown;                                     \
    hs[i] = hown;                                                           \
  }

// load a 4-step block of xg (clamped indices -> always-valid rows)
#define LDBLK(DR, DZ, DN, T0)                                               \
  {                                                                         \
    int u0 = (T0)     < tcnt ? (T0)     : tcnt - 1;                         \
    int u1 = (T0) + 1 < tcnt ? (T0) + 1 : tcnt - 1;                         \
    int u2 = (T0) + 2 < tcnt ? (T0) + 2 : tcnt - 1;                         \
    int u3 = (T0) + 3 < tcnt ? (T0) + 3 : tcnt - 1;                         \
    const float* p0 = xgv + (size_t)u0 * G3;                                \
    const float* p1 = xgv + (size_t)u1 * G3;                                \
    const float* p2 = xgv + (size_t)u2 * G3;                                \
    const float* p3 = xgv + (size_t)u3 * G3;                                \
    DR.x = p0[i];  DZ.x = p0[64 + i];  DN.x = p0[128 + i];                  \
    DR.y = p1[i];  DZ.y = p1[64 + i];  DN.y = p1[128 + i];                  \
    DR.z = p2[i];  DZ.z = p2[64 + i];  DN.z = p2[128 + i];                  \
    DR.w = p3[i];  DZ.w = p3[64 + i];  DN.w = p3[128 + i];                  \
  }

// ---------------- K2: sequential GRU recurrence.
// v5: single wave per variable, all 3 gates per lane. The 192 weight floats
// MUST live in VGPRs: v3/v4 allocated only 124 (allocator re-sank the weight
// loads into the loop -> ~1750 cyc/step, 95% memory-wait). Fixes:
//  - amdgpu_waves_per_eu(1,1): target exactly 1 wave/EU -> 512-VGPR budget
//    (launch_bounds(64,1) was a no-op: min-waves default is already 1)
//  - empty-asm pin after the weight loads: loads cannot be sunk/remat'd
//  - 4-step blocked xg prefetch (float4/gate, static indexing): ~1600 cyc
//    of L3/HBM latency coverage vs ~800 at depth 2.
__global__ __attribute__((amdgpu_flat_work_group_size(64, 64),
                          amdgpu_waves_per_eu(1, 1))) void k_rec(
    const float* __restrict__ xg, const int* __restrict__ lengths,
    const float* __restrict__ W_hh, const float* __restrict__ b_hh,
    float* __restrict__ h, int c, int CT) {
    int v = blockIdx.x;
    int i = threadIdx.x;  // 0..63 = hidden index
    int len = lengths[v];
    int rem = len - c * CT;
    int tcnt = rem < 0 ? 0 : (rem > CT ? CT : rem);

    __shared__ __align__(16) float hs[H];

    // own weight rows as float2[32] each (192 VGPRs)
    float2 wr[32], wz[32], wn[32];
    {
        const float2* Wr = (const float2*)&W_hh[(size_t)i * H];
        const float2* Wz = (const float2*)&W_hh[(size_t)(64 + i) * H];
        const float2* Wn = (const float2*)&W_hh[(size_t)(128 + i) * H];
#pragma unroll
        for (int k = 0; k < 32; k++) { wr[k] = Wr[k]; wz[k] = Wz[k]; wn[k] = Wn[k]; }
    }
    // pin every weight value into a VGPR here; loads can no longer be sunk
#pragma unroll
    for (int k = 0; k < 32; k++) {
        asm volatile("" : "+v"(wr[k].x), "+v"(wr[k].y),
                          "+v"(wz[k].x), "+v"(wz[k].y),
                          "+v"(wn[k].x), "+v"(wn[k].y));
    }
    float br = b_hh[i], bz = b_hh[64 + i], bn = b_hh[128 + i];

    float hown = h[v * H + i];
    hs[i] = hown;
    // single wave: lockstep + in-order LDS pipe orders store before reads

    const float* xgv = xg + (size_t)v * CT * G3;

    if (tcnt > 0) {
        float4 cr4, cz4, cn4;
        LDBLK(cr4, cz4, cn4, 0);
        for (int t0 = 0; t0 < tcnt; t0 += 4) {
            float4 pr4, pz4, pn4;
            LDBLK(pr4, pz4, pn4, t0 + 4);   // issue next block's 12 loads early
            GRU_STEP(cr4.x, cz4.x, cn4.x, t0 + 0);
            GRU_STEP(cr4.y, cz4.y, cn4.y, t0 + 1);
            GRU_STEP(cr4.z, cz4.z, cn4.z, t0 + 2);
            GRU_STEP(cr4.w, cz4.w, cn4.w, t0 + 3);
            cr4 = pr4; cz4 = pz4; cn4 = pn4;
        }
        h[v * H + i] = hown;
    }
}

// ---------------- K2F: fully-fused fallback (tiny workspace). Slow but correct.
__global__ __launch_bounds__(192) void k_rec_fused(
    const float* __restrict__ emb, const int* __restrict__ lengths,
    const float* __restrict__ W_ih, const float* __restrict__ b_ih,
    const float* __restrict__ W_hh, const float* __restrict__ b_hh,
    float* __restrict__ h) {
    int v  = blockIdx.x;
    int th = threadIdx.x;
    int len = lengths[v];

    __shared__ __align__(16) float hs[H];
    __shared__ __align__(16) float es[ED];
    __shared__ float znbuf[128];
    __shared__ float xnbuf[64];

    float4 w4[16];
#pragma unroll
    for (int k4 = 0; k4 < 16; k4++)
        w4[k4] = *(const float4*)&W_hh[(size_t)th * H + k4 * 4];
    float bhh = b_hh[th];
    float bih = b_ih[th];
    if (th < H) hs[th] = 0.f;
    const float* ev = emb + (size_t)v * TMAX * ED;
    const float* wrow = W_ih + (size_t)th * ED;

    for (int t = 0; t < len; t++) {
        __syncthreads();
        for (int i = th; i < 128; i += 192)
            *(float4*)&es[i * 4] = *(const float4*)&ev[(size_t)t * ED + i * 4];
        __syncthreads();
        float xgt = bih;
        for (int k4 = 0; k4 < 128; k4++) {
            float4 wv = *(const float4*)&wrow[k4 * 4];
            float4 e4 = *(float4*)&es[k4 * 4];
            xgt += wv.x * e4.x + wv.y * e4.y + wv.z * e4.z + wv.w * e4.w;
        }
        float hg = bhh;
#pragma unroll
        for (int k4 = 0; k4 < 16; k4++) {
            float4 h4 = *(float4*)&hs[k4 * 4];
            hg += w4[k4].x * h4.x + w4[k4].y * h4.y + w4[k4].z * h4.z + w4[k4].w * h4.w;
        }
        if (th >= H && th < 128) znbuf[th - H] = hg + xgt;
        if (th >= 128) { znbuf[th - H] = hg; xnbuf[th - 128] = xgt; }
        __syncthreads();
        if (th < H) {
            float r = 1.f / (1.f + expf(-(hg + xgt)));
            float z = 1.f / (1.f + expf(-znbuf[th]));
            float n = tanhf(xnbuf[th] + r * znbuf[64 + th]);
            float hold = hs[th];
            hs[th] = (1.f - z) * n + z * hold;
        }
    }
    __syncthreads();
    if (th < H) h[v * H + th] = hs[th];
}

// ---------------- K3a: hid[o] = relu(b1[o] + W1[o,:] · concat)
__global__ __launch_bounds__(256) void k_mlp1(
    const float* __restrict__ h, const float* __restrict__ W1,
    const float* __restrict__ b1, float* __restrict__ hid) {
    int o = blockIdx.x, th = threadIdx.x;
    const float* w = W1 + (size_t)o * (V * H);
    float s = 0.f;
#pragma unroll
    for (int r = 0; r < 4; r++) {
        int i = (th + r * 256) * 4;
        float4 a = *(const float4*)&w[i];
        float4 b = *(const float4*)&h[i];
        s += a.x * b.x + a.y * b.y + a.z * b.z + a.w * b.w;
    }
    __shared__ float red[4];
    for (int off = 32; off; off >>= 1) s += __shfl_down(s, off);
    if ((th & 63) == 0) red[th >> 6] = s;
    __syncthreads();
    if (th == 0) {
        float tot = red[0] + red[1] + red[2] + red[3] + b1[o];
        hid[o] = tot > 0.f ? tot : 0.f;
    }
}

// ---------------- K3b: out = b2 + W2 · hid
__global__ void k_mlp2(const float* __restrict__ hid, const float* __restrict__ W2,
                       const float* __restrict__ b2, float* __restrict__ out) {
    int th = threadIdx.x;
    float s = hid[th] * W2[th];
    for (int off = 32; off; off >>= 1) s += __shfl_down(s, off);
    if (th == 0) out[0] = s + b2[0];
}

extern "C" void kernel_launch(void* const* d_in, const int* in_sizes, int n_in,
                              void* d_out, int out_size, void* d_ws, size_t ws_size,
                              hipStream_t stream) {
    const float* emb     = (const float*)d_in[0];
    const int*   lengths = (const int*)d_in[1];
    const float* W_ih    = (const float*)d_in[2];
    const float* W_hh    = (const float*)d_in[3];
    const float* b_ih    = (const float*)d_in[4];
    const float* b_hh    = (const float*)d_in[5];
    const float* W1      = (const float*)d_in[6];
    const float* b1      = (const float*)d_in[7];
    const float* W2      = (const float*)d_in[8];
    const float* b2      = (const float*)d_in[9];
    float* out = (float*)d_out;
    float* wsf = (float*)d_ws;

    const size_t tail = (size_t)V * H + V;  // h + hid (floats)
    int CT = 0;
    const int cts[7] = {2048, 1024, 512, 256, 128, 64, 32};
    for (int i = 0; i < 7; i++) {
        size_t need = ((size_t)V * cts[i] * G3 + tail) * sizeof(float);
        if (need <= ws_size) { CT = cts[i]; break; }
    }

    if (CT > 0) {
        float* xg  = wsf;
        float* hbf = wsf + (size_t)V * CT * G3;
        float* hid = hbf + (size_t)V * H;
        k_init<<<dim3((V * H + 255) / 256), dim3(256), 0, stream>>>(hbf);
        int nch = TMAX / CT;
        for (int c = 0; c < nch; c++) {
            if (CT >= 256)
                k_gemm<<<dim3(CT / 128, V), dim3(256), 0, stream>>>(emb, lengths, W_ih, b_ih, xg, c, CT);
            else
                k_gemm_s<<<dim3(CT / 32, V), dim3(256), 0, stream>>>(emb, lengths, W_ih, b_ih, xg, c, CT);
            k_rec<<<dim3(V), dim3(64), 0, stream>>>(xg, lengths, W_hh, b_hh, hbf, c, CT);
        }
        k_mlp1<<<dim3(V), dim3(256), 0, stream>>>(hbf, W1, b1, hid);
        k_mlp2<<<dim3(1), dim3(64), 0, stream>>>(hid, W2, b2, out);
    } else {
        float* hbf = wsf;
        float* hid = hbf + (size_t)V * H;
        k_rec_fused<<<dim3(V), dim3(G3), 0, stream>>>(emb, lengths, W_ih, b_ih, W_hh, b_hh, hbf);
        k_mlp1<<<dim3(V), dim3(256), 0, stream>>>(hbf, W1, b1, hid);
        k_mlp2<<<dim3(1), dim3(64), 0, stream>>>(hid, W2, b2, out);
    }
}

// Round 5
// 1613.132 us; speedup vs baseline: 1.3715x; 1.2519x over previous
//
#include <hip/hip_runtime.h>
#include <math.h>

#define V 64
#define TMAX 2048
#define ED 512
#define H 64
#define G3 192

// packed fp32 FMA: acc.{x,y} += a.{x,y} * b.{x,y}  (one VALU instr)
__device__ __forceinline__ void pk_fma(float2& acc, float2 a, float2 b) {
    asm("v_pk_fma_f32 %0, %1, %2, %0" : "+v"(acc) : "v"(a), "v"(b));
}

// ---------------- K0: zero the persistent hidden state ----------------
__global__ void k_init(float* __restrict__ h) {
    int i = blockIdx.x * blockDim.x + threadIdx.x;
    if (i < V * H) h[i] = 0.f;
}

// ---------------- K1: xg[v, tl, g] = b_ih[g] + sum_k emb[v,t,k] * W_ih[g,k]
// 128t x 192g block tile, 8t x 12g register micro-tile per thread.
// XOR column swizzle on LDS (row stride 64 floats, no pad).
__global__ __launch_bounds__(256)
__attribute__((amdgpu_waves_per_eu(2, 2))) void k_gemm(
    const float* __restrict__ emb, const int* __restrict__ lengths,
    const float* __restrict__ W_ih, const float* __restrict__ b_ih,
    float* __restrict__ xg, int c, int CT) {
    int v   = blockIdx.y;
    int tl0 = blockIdx.x * 128;
    int t0  = c * CT + tl0;
    int len = lengths[v];
    if (t0 >= len) return;  // nothing in this tile is ever read

    __shared__ __align__(16) float Es[128 * 64];  // 32 KB, swizzled
    __shared__ __align__(16) float Ws[G3 * 64];   // 48 KB, swizzled

    int th = threadIdx.x;
    int tb = th & 15;   // t-block: rows tb*8 .. tb*8+7
    int gb = th >> 4;   // g-block: gates gb*12 .. gb*12+11
    int eswz = tb & 7;  // read-side swizzle for this thread's 8 E rows

    float acc[8][12];
#pragma unroll
    for (int i = 0; i < 8; i++)
#pragma unroll
        for (int j = 0; j < 12; j++) acc[i][j] = 0.f;

    const float* ebase = emb + (size_t)(v * TMAX + t0) * ED;

    for (int kc = 0; kc < 8; kc++) {
        // stage E tile: 128x64 floats = 2048 float4, 8 per thread
#pragma unroll
        for (int r = 0; r < 8; r++) {
            int i = th + r * 256;
            int row = i >> 4, pos = i & 15;
            *(float4*)&Es[row * 64 + (pos ^ ((row >> 3) & 7)) * 4] =
                *(const float4*)&ebase[(size_t)row * ED + kc * 64 + pos * 4];
        }
        // stage W tile: 192x64 floats = 3072 float4, 12 per thread
#pragma unroll
        for (int r = 0; r < 12; r++) {
            int i = th + r * 256;
            int row = i >> 4, pos = i & 15;
            *(float4*)&Ws[row * 64 + (pos ^ (row & 7)) * 4] =
                *(const float4*)&W_ih[(size_t)row * ED + kc * 64 + pos * 4];
        }
        __syncthreads();
#pragma unroll 2
        for (int k4 = 0; k4 < 16; k4++) {
            float4 e[8];
#pragma unroll
            for (int i = 0; i < 8; i++)
                e[i] = *(float4*)&Es[(tb * 8 + i) * 64 + (k4 ^ eswz) * 4];
#pragma unroll
            for (int j = 0; j < 12; j++) {
                int g = gb * 12 + j;
                float4 w = *(float4*)&Ws[g * 64 + (k4 ^ (g & 7)) * 4];
#pragma unroll
                for (int i = 0; i < 8; i++)
                    acc[i][j] += e[i].x * w.x + e[i].y * w.y + e[i].z * w.z + e[i].w * w.w;
            }
        }
        __syncthreads();
    }

    float4 bv[3];
#pragma unroll
    for (int j4 = 0; j4 < 3; j4++)
        bv[j4] = *(const float4*)&b_ih[gb * 12 + j4 * 4];

#pragma unroll
    for (int i = 0; i < 8; i++) {
        size_t ob = ((size_t)(v * CT + tl0 + tb * 8 + i)) * G3 + gb * 12;
#pragma unroll
        for (int j4 = 0; j4 < 3; j4++) {
            float4 o;
            o.x = acc[i][j4 * 4 + 0] + bv[j4].x;
            o.y = acc[i][j4 * 4 + 1] + bv[j4].y;
            o.z = acc[i][j4 * 4 + 2] + bv[j4].z;
            o.w = acc[i][j4 * 4 + 3] + bv[j4].w;
            *(float4*)&xg[ob + j4 * 4] = o;
        }
    }
}

// ---------------- K1s: small-CT fallback (32x192 tile) ----------------
__global__ __launch_bounds__(256) void k_gemm_s(
    const float* __restrict__ emb, const int* __restrict__ lengths,
    const float* __restrict__ W_ih, const float* __restrict__ b_ih,
    float* __restrict__ xg, int c, int CT) {
    int v   = blockIdx.y;
    int tl0 = blockIdx.x * 32;
    int t0  = c * CT + tl0;
    int len = lengths[v];
    if (t0 >= len) return;

    __shared__ __align__(16) float Es[32][68];
    __shared__ __align__(16) float Ws[G3][68];

    int th = threadIdx.x;
    int tq = th & 31;
    int gq = th >> 5;

    float acc[24];
#pragma unroll
    for (int j = 0; j < 24; j++) acc[j] = 0.f;

    for (int kc = 0; kc < 8; kc++) {
#pragma unroll
        for (int r = 0; r < 2; r++) {
            int i = th + r * 256;
            int row = i >> 4, pos = i & 15;
            *(float4*)&Es[row][pos * 4] =
                *(const float4*)&emb[((size_t)(v * TMAX + t0 + row)) * ED + kc * 64 + pos * 4];
        }
#pragma unroll
        for (int r = 0; r < 12; r++) {
            int i = th + r * 256;
            int row = i >> 4, pos = i & 15;
            *(float4*)&Ws[row][pos * 4] =
                *(const float4*)&W_ih[(size_t)row * ED + kc * 64 + pos * 4];
        }
        __syncthreads();
#pragma unroll
        for (int k4 = 0; k4 < 16; k4++) {
            float4 e4 = *(float4*)&Es[tq][k4 * 4];
#pragma unroll
            for (int j = 0; j < 24; j++) {
                float4 w4 = *(float4*)&Ws[gq * 24 + j][k4 * 4];
                acc[j] += e4.x * w4.x + e4.y * w4.y + e4.z * w4.z + e4.w * w4.w;
            }
        }
        __syncthreads();
    }

    size_t ob = ((size_t)(v * CT + tl0 + tq)) * G3 + gq * 24;
#pragma unroll
    for (int j4 = 0; j4 < 6; j4++) {
        float4 o;
        o.x = acc[j4 * 4 + 0] + b_ih[gq * 24 + j4 * 4 + 0];
        o.y = acc[j4 * 4 + 1] + b_ih[gq * 24 + j4 * 4 + 1];
        o.z = acc[j4 * 4 + 2] + b_ih[gq * 24 + j4 * 4 + 2];
        o.w = acc[j4 * 4 + 3] + b_ih[gq * 24 + j4 * 4 + 3];
        *(float4*)&xg[ob + j4 * 4] = o;
    }
}

// load 4 consecutive steps of this lane's own xg element (clamped indices)
#define LD4(DST, T0)                                                        \
  {                                                                         \
    int u0 = (T0)     < tcnt ? (T0)     : tcnt - 1;                         \
    int u1 = (T0) + 1 < tcnt ? (T0) + 1 : tcnt - 1;                         \
    int u2 = (T0) + 2 < tcnt ? (T0) + 2 : tcnt - 1;                         \
    int u3 = (T0) + 3 < tcnt ? (T0) + 3 : tcnt - 1;                         \
    DST.x = xgt[(size_t)u0 * G3];                                           \
    DST.y = xgt[(size_t)u1 * G3];                                           \
    DST.z = xgt[(size_t)u2 * G3];                                           \
    DST.w = xgt[(size_t)u3 * G3];                                           \
  }

// one GRU timestep for the 3-wave layout. XV = this lane's xg value at step
// TT. Dead steps (TT>=tcnt, clamped XV) compute finite garbage that the
// cndmask on hprev discards; hs rewrite of unchanged hprev is harmless.
#define STEP(XV, TT)                                                        \
  {                                                                         \
    float2 a0 = {0.f, 0.f}, a1 = {0.f, 0.f}, a2 = {0.f, 0.f},               \
           a3 = {0.f, 0.f};                                                 \
    _Pragma("unroll")                                                       \
    for (int k4 = 0; k4 < 16; k4 += 2) {                                    \
      float4 ha = *(const float4*)&hs[k4 * 4];                              \
      float4 hb = *(const float4*)&hs[k4 * 4 + 4];                          \
      pk_fma(a0, make_float2(w4[k4].x, w4[k4].y), make_float2(ha.x, ha.y)); \
      pk_fma(a1, make_float2(w4[k4].z, w4[k4].w), make_float2(ha.z, ha.w)); \
      pk_fma(a2, make_float2(w4[k4+1].x, w4[k4+1].y),                       \
                 make_float2(hb.x, hb.y));                                  \
      pk_fma(a3, make_float2(w4[k4+1].z, w4[k4+1].w),                       \
                 make_float2(hb.z, hb.w));                                  \
    }                                                                       \
    float hg = bhh + ((a0.x + a0.y) + (a1.x + a1.y)) +                      \
                     ((a2.x + a2.y) + (a3.x + a3.y));                       \
    if (gate == 0) {                                                        \
      rz[o] = __fdividef(1.f, 1.f + __expf(-(hg + (XV))));                  \
    } else if (gate == 1) {                                                 \
      rz[64 + o] = __fdividef(1.f, 1.f + __expf(-(hg + (XV))));             \
    }                                                                       \
    __syncthreads();                                                        \
    if (gate == 2) {                                                        \
      float rv = rz[o], zv = rz[64 + o];                                    \
      float e2 = __expf(2.f * ((XV) + rv * hg));                            \
      float nv = 1.f - __fdividef(2.f, e2 + 1.f);                           \
      float hnew = (1.f - zv) * nv + zv * hprev;                            \
      hprev = ((TT) < tcnt) ? hnew : hprev;                                 \
      hs[o] = hprev;                                                        \
    }                                                                       \
    __syncthreads();                                                        \
  }

// ---------------- K2: sequential GRU recurrence.
// v6: back to 3 waves (192 threads, one gate-row = 64 weight floats/lane),
// which fits UNDER the register budget the allocator has demonstrated it
// will give (~136 VGPRs; v5's 232-VGPR single-wave need was refused twice,
// weights were re-fetched from L1/L2 every step in ALL prior versions).
// Pin makes the 16 float4 weight loads un-rematerializable -> resident.
// Step restructure vs v1: r/z sigmoids pre-barrier (activated values cross
// LDS, not raw pre-activations); n-lane owns the h-update with hprev in a
// register; one coalesced xg load/lane/step with a 4-step prefetch block.
__global__ __attribute__((amdgpu_flat_work_group_size(192, 192),
                          amdgpu_waves_per_eu(1, 1))) void k_rec(
    const float* __restrict__ xg, const int* __restrict__ lengths,
    const float* __restrict__ W_hh, const float* __restrict__ b_hh,
    float* __restrict__ h, int c, int CT) {
    int v    = blockIdx.x;
    int th   = threadIdx.x;  // 0..191
    int o    = th & 63;      // output index
    int gate = th >> 6;      // 0=r, 1=z, 2=n (PyTorch gate order)
    int len  = lengths[v];
    int rem  = len - c * CT;
    int tcnt = rem < 0 ? 0 : (rem > CT ? CT : rem);

    __shared__ __align__(16) float hs[H];
    __shared__ float rz[128];  // [0..63]=r activated, [64..127]=z activated

    // own gate row: 64 floats = 16 float4 (~64 VGPRs, under budget)
    float4 w4[16];
#pragma unroll
    for (int k4 = 0; k4 < 16; k4++)
        w4[k4] = *(const float4*)&W_hh[(size_t)th * H + k4 * 4];
    // pin: volatile-asm results cannot be rematerialized by the scheduler
#pragma unroll
    for (int k4 = 0; k4 < 16; k4++)
        asm volatile("" : "+v"(w4[k4].x), "+v"(w4[k4].y),
                          "+v"(w4[k4].z), "+v"(w4[k4].w));
    float bhh = b_hh[th];

    float hprev = h[v * H + o];
    if (th < H) hs[th] = hprev;
    __syncthreads();

    const float* xgt = xg + (size_t)v * CT * G3 + th;

    if (tcnt > 0) {
        float4 xc, xp;
        LD4(xc, 0);
        for (int t0 = 0; t0 < tcnt; t0 += 4) {
            LD4(xp, t0 + 4);  // prefetch next block (independent of chain)
            STEP(xc.x, t0 + 0);
            STEP(xc.y, t0 + 1);
            STEP(xc.z, t0 + 2);
            STEP(xc.w, t0 + 3);
            xc = xp;
        }
        if (gate == 2) h[v * H + o] = hprev;
    }
}

// ---------------- K2F: fully-fused fallback (tiny workspace). Slow but correct.
__global__ __launch_bounds__(192) void k_rec_fused(
    const float* __restrict__ emb, const int* __restrict__ lengths,
    const float* __restrict__ W_ih, const float* __restrict__ b_ih,
    const float* __restrict__ W_hh, const float* __restrict__ b_hh,
    float* __restrict__ h) {
    int v  = blockIdx.x;
    int th = threadIdx.x;
    int len = lengths[v];

    __shared__ __align__(16) float hs[H];
    __shared__ __align__(16) float es[ED];
    __shared__ float znbuf[128];
    __shared__ float xnbuf[64];

    float4 w4[16];
#pragma unroll
    for (int k4 = 0; k4 < 16; k4++)
        w4[k4] = *(const float4*)&W_hh[(size_t)th * H + k4 * 4];
    float bhh = b_hh[th];
    float bih = b_ih[th];
    if (th < H) hs[th] = 0.f;
    const float* ev = emb + (size_t)v * TMAX * ED;
    const float* wrow = W_ih + (size_t)th * ED;

    for (int t = 0; t < len; t++) {
        __syncthreads();
        for (int i = th; i < 128; i += 192)
            *(float4*)&es[i * 4] = *(const float4*)&ev[(size_t)t * ED + i * 4];
        __syncthreads();
        float xgt = bih;
        for (int k4 = 0; k4 < 128; k4++) {
            float4 wv = *(const float4*)&wrow[k4 * 4];
            float4 e4 = *(float4*)&es[k4 * 4];
            xgt += wv.x * e4.x + wv.y * e4.y + wv.z * e4.z + wv.w * e4.w;
        }
        float hg = bhh;
#pragma unroll
        for (int k4 = 0; k4 < 16; k4++) {
            float4 h4 = *(float4*)&hs[k4 * 4];
            hg += w4[k4].x * h4.x + w4[k4].y * h4.y + w4[k4].z * h4.z + w4[k4].w * h4.w;
        }
        if (th >= H && th < 128) znbuf[th - H] = hg + xgt;
        if (th >= 128) { znbuf[th - H] = hg; xnbuf[th - 128] = xgt; }
        __syncthreads();
        if (th < H) {
            float r = 1.f / (1.f + expf(-(hg + xgt)));
            float z = 1.f / (1.f + expf(-znbuf[th]));
            float n = tanhf(xnbuf[th] + r * znbuf[64 + th]);
            float hold = hs[th];
            hs[th] = (1.f - z) * n + z * hold;
        }
    }
    __syncthreads();
    if (th < H) h[v * H + th] = hs[th];
}

// ---------------- K3a: hid[o] = relu(b1[o] + W1[o,:] · concat)
__global__ __launch_bounds__(256) void k_mlp1(
    const float* __restrict__ h, const float* __restrict__ W1,
    const float* __restrict__ b1, float* __restrict__ hid) {
    int o = blockIdx.x, th = threadIdx.x;
    const float* w = W1 + (size_t)o * (V * H);
    float s = 0.f;
#pragma unroll
    for (int r = 0; r < 4; r++) {
        int i = (th + r * 256) * 4;
        float4 a = *(const float4*)&w[i];
        float4 b = *(const float4*)&h[i];
        s += a.x * b.x + a.y * b.y + a.z * b.z + a.w * b.w;
    }
    __shared__ float red[4];
    for (int off = 32; off; off >>= 1) s += __shfl_down(s, off);
    if ((th & 63) == 0) red[th >> 6] = s;
    __syncthreads();
    if (th == 0) {
        float tot = red[0] + red[1] + red[2] + red[3] + b1[o];
        hid[o] = tot > 0.f ? tot : 0.f;
    }
}

// ---------------- K3b: out = b2 + W2 · hid
__global__ void k_mlp2(const float* __restrict__ hid, const float* __restrict__ W2,
                       const float* __restrict__ b2, float* __restrict__ out) {
    int th = threadIdx.x;
    float s = hid[th] * W2[th];
    for (int off = 32; off; off >>= 1) s += __shfl_down(s, off);
    if (th == 0) out[0] = s + b2[0];
}

extern "C" void kernel_launch(void* const* d_in, const int* in_sizes, int n_in,
                              void* d_out, int out_size, void* d_ws, size_t ws_size,
                              hipStream_t stream) {
    const float* emb     = (const float*)d_in[0];
    const int*   lengths = (const int*)d_in[1];
    const float* W_ih    = (const float*)d_in[2];
    const float* W_hh    = (const float*)d_in[3];
    const float* b_ih    = (const float*)d_in[4];
    const float* b_hh    = (const float*)d_in[5];
    const float* W1      = (const float*)d_in[6];
    const float* b1      = (const float*)d_in[7];
    const float* W2      = (const float*)d_in[8];
    const float* b2      = (const float*)d_in[9];
    float* out = (float*)d_out;
    float* wsf = (float*)d_ws;

    const size_t tail = (size_t)V * H + V;  // h + hid (floats)
    int CT = 0;
    const int cts[7] = {2048, 1024, 512, 256, 128, 64, 32};
    for (int i = 0; i < 7; i++) {
        size_t need = ((size_t)V * cts[i] * G3 + tail) * sizeof(float);
        if (need <= ws_size) { CT = cts[i]; break; }
    }

    if (CT > 0) {
        float* xg  = wsf;
        float* hbf = wsf + (size_t)V * CT * G3;
        float* hid = hbf + (size_t)V * H;
        k_init<<<dim3((V * H + 255) / 256), dim3(256), 0, stream>>>(hbf);
        int nch = TMAX / CT;
        for (int c = 0; c < nch; c++) {
            if (CT >= 256)
                k_gemm<<<dim3(CT / 128, V), dim3(256), 0, stream>>>(emb, lengths, W_ih, b_ih, xg, c, CT);
            else
                k_gemm_s<<<dim3(CT / 32, V), dim3(256), 0, stream>>>(emb, lengths, W_ih, b_ih, xg, c, CT);
            k_rec<<<dim3(V), dim3(G3), 0, stream>>>(xg, lengths, W_hh, b_hh, hbf, c, CT);
        }
        k_mlp1<<<dim3(V), dim3(256), 0, stream>>>(hbf, W1, b1, hid);
        k_mlp2<<<dim3(1), dim3(64), 0, stream>>>(hid, W2, b2, out);
    } else {
        float* hbf = wsf;
        float* hid = hbf + (size_t)V * H;
        k_rec_fused<<<dim3(V), dim3(G3), 0, stream>>>(emb, lengths, W_ih, b_ih, W_hh, b_hh, hbf);
        k_mlp1<<<dim3(V), dim3(256), 0, stream>>>(hbf, W1, b1, hid);
        k_mlp2<<<dim3(1), dim3(64), 0, stream>>>(hid, W2, b2, out);
    }
}